// Round 3
// baseline (466.438 us; speedup 1.0000x reference)
//
#include <hip/hip_runtime.h>
#include <math.h>
#include <stdint.h>

#define W 4
#define NUM_HEADS 32
#define HEAD_SIZE 128
#define G 8            // kv heads
#define QPG 4          // query heads per kv head
#define BLOCK_SZ 16
#define NUM_BLOCKS 1024
#define MAX_BLOCKS 32
#define S 32           // num seqs
#define SPLIT 2        // blocks per (w,s,g): block p takes chunks c ≡ p (mod 2)
#define NPART (W * SPLIT)
#define SCALE 0.08838834764831845f  // 1/sqrt(128)
#define NEG_BIG (-1e30f)

#define BLK_STRIDE (G * BLOCK_SZ * HEAD_SIZE)   // elems per paged block (16384)
#define WG_STRIDE  ((size_t)NUM_BLOCKS * BLK_STRIDE)
#define CHUNK_ELEMS (BLOCK_SZ * HEAD_SIZE)      // 2048 floats = 8 KB (one head's rows of one block)

typedef const __attribute__((address_space(1))) uint32_t* gas_ptr;
typedef __attribute__((address_space(3))) uint32_t* las_ptr;

// Async global->LDS copy of one chunk: 2048 floats K + 2048 floats V, fully
// contiguous in both global and LDS. Per wave: 2x256-float rounds for each of
// K and V; LDS dest is wave-uniform base, HW scatters lane*16B.
__device__ __forceinline__ void stage_chunk(const float* __restrict__ ksrc,
                                            const float* __restrict__ vsrc,
                                            float* kv_dst, int tid)
{
    const int wv = tid >> 6;          // wave id 0..3
    const int ln = tid & 63;
    const int b0 = wv * 512;
    const int b1 = b0 + 256;
    __builtin_amdgcn_global_load_lds((gas_ptr)(ksrc + b0 + ln * 4), (las_ptr)(kv_dst + b0),               16, 0, 0);
    __builtin_amdgcn_global_load_lds((gas_ptr)(ksrc + b1 + ln * 4), (las_ptr)(kv_dst + b1),               16, 0, 0);
    __builtin_amdgcn_global_load_lds((gas_ptr)(vsrc + b0 + ln * 4), (las_ptr)(kv_dst + CHUNK_ELEMS + b0), 16, 0, 0);
    __builtin_amdgcn_global_load_lds((gas_ptr)(vsrc + b1 + ln * 4), (las_ptr)(kv_dst + CHUNK_ELEMS + b1), 16, 0, 0);
}

// One block per (w,s,g,p). Chunks (= paged blocks) staged to LDS double-buffered
// with async prefetch; 8 half-wave online-softmax accumulators, each takes the
// token pair (accid, accid+8) of every chunk. Lane l owns dims [4l,4l+4).
__global__ __launch_bounds__(256, 4)
void pa_partial_kernel(const float* __restrict__ query,
                       const float* __restrict__ key_cache,
                       const float* __restrict__ value_cache,
                       const int* __restrict__ block_tables,
                       const int* __restrict__ context_lens,
                       float* __restrict__ acc_ws,
                       float* __restrict__ m_ws,
                       float* __restrict__ e_ws)
{
    int bx = blockIdx.x;                 // ((w*S + s)*G + g)*SPLIT + p
    const int p = bx & 1; bx >>= 1;
    const int g = bx % G; bx /= G;
    const int s = bx % S;
    const int w = bx / S;

    const int tid   = threadIdx.x;
    const int accid = tid >> 5;          // 0..7
    const int lane  = tid & 31;
    const int d0    = lane * 4;

    __shared__ float smem[2 * 2 * CHUNK_ELEMS];   // 2 bufs x (K 8KB + V 8KB) = 32 KB
    __shared__ float sm_m[8][QPG], sm_e[8][QPG];

    const int ctx    = context_lens[w * S + s];
    const int nc_all = (ctx + BLOCK_SZ - 1) >> 4;
    const int cnt    = (nc_all - p + 1) >> 1;     // chunks handled by this block
    const int* bt = block_tables + ((size_t)w * S + s) * MAX_BLOCKS;
    const float* kbase = key_cache   + (size_t)w * WG_STRIDE + (size_t)g * CHUNK_ELEMS;
    const float* vbase = value_cache + (size_t)w * WG_STRIDE + (size_t)g * CHUNK_ELEMS;

    float4 qf[QPG];
#pragma unroll
    for (int qi = 0; qi < QPG; ++qi)
        qf[qi] = *reinterpret_cast<const float4*>(
            query + ((size_t)s * NUM_HEADS + g * QPG + qi) * HEAD_SIZE + d0);

    float  m_i[QPG], e_i[QPG];
    float4 acc[QPG];
#pragma unroll
    for (int qi = 0; qi < QPG; ++qi) {
        m_i[qi] = NEG_BIG; e_i[qi] = 0.f;
        acc[qi] = make_float4(0.f, 0.f, 0.f, 0.f);
    }

    if (cnt > 0) {
        const size_t bb = (size_t)bt[p] * BLK_STRIDE;
        stage_chunk(kbase + bb, vbase + bb, smem, tid);
    }
    __syncthreads();     // drains the async loads (compiler emits vmcnt(0) at barrier)

    int buf = 0;
    for (int i = 0; i < cnt; ++i) {
        const int c = p + 2 * i;
        if (i + 1 < cnt) {                       // prefetch next chunk into other buffer
            const size_t bb = (size_t)bt[c + 2] * BLK_STRIDE;
            stage_chunk(kbase + bb, vbase + bb, smem + (buf ^ 1) * (2 * CHUNK_ELEMS), tid);
        }

        const float* kb = smem + buf * (2 * CHUNK_ELEMS);
        const float* vb = kb + CHUNK_ELEMS;
        const int gt0 = (c << 4) + accid;        // global token of pair-first
        if (gt0 < ctx) {                         // uniform within the half-wave
            const float4 k1 = *reinterpret_cast<const float4*>(kb + accid * HEAD_SIZE + d0);
            const float4 v1 = *reinterpret_cast<const float4*>(vb + accid * HEAD_SIZE + d0);
            const float4 k2 = *reinterpret_cast<const float4*>(kb + (accid + 8) * HEAD_SIZE + d0);
            const float4 v2 = *reinterpret_cast<const float4*>(vb + (accid + 8) * HEAD_SIZE + d0);

            float4 dv1, dv2;
            dv1.x = qf[0].x*k1.x + qf[0].y*k1.y + qf[0].z*k1.z + qf[0].w*k1.w;
            dv1.y = qf[1].x*k1.x + qf[1].y*k1.y + qf[1].z*k1.z + qf[1].w*k1.w;
            dv1.z = qf[2].x*k1.x + qf[2].y*k1.y + qf[2].z*k1.z + qf[2].w*k1.w;
            dv1.w = qf[3].x*k1.x + qf[3].y*k1.y + qf[3].z*k1.z + qf[3].w*k1.w;
            dv2.x = qf[0].x*k2.x + qf[0].y*k2.y + qf[0].z*k2.z + qf[0].w*k2.w;
            dv2.y = qf[1].x*k2.x + qf[1].y*k2.y + qf[1].z*k2.z + qf[1].w*k2.w;
            dv2.z = qf[2].x*k2.x + qf[2].y*k2.y + qf[2].z*k2.z + qf[2].w*k2.w;
            dv2.w = qf[3].x*k2.x + qf[3].y*k2.y + qf[3].z*k2.z + qf[3].w*k2.w;
#pragma unroll
            for (int o = 16; o > 0; o >>= 1) {   // stays within the 32-lane half
                dv1.x += __shfl_xor(dv1.x, o); dv1.y += __shfl_xor(dv1.y, o);
                dv1.z += __shfl_xor(dv1.z, o); dv1.w += __shfl_xor(dv1.w, o);
                dv2.x += __shfl_xor(dv2.x, o); dv2.y += __shfl_xor(dv2.y, o);
                dv2.z += __shfl_xor(dv2.z, o); dv2.w += __shfl_xor(dv2.w, o);
            }
            const float l1[QPG] = {dv1.x*SCALE, dv1.y*SCALE, dv1.z*SCALE, dv1.w*SCALE};
            float l2[QPG] = {dv2.x*SCALE, dv2.y*SCALE, dv2.z*SCALE, dv2.w*SCALE};
            const bool vld2 = (gt0 + 8) < ctx;
#pragma unroll
            for (int qi = 0; qi < QPG; ++qi) if (!vld2) l2[qi] = NEG_BIG;

#pragma unroll
            for (int qi = 0; qi < QPG; ++qi) {
                const float mn    = fmaxf(m_i[qi], fmaxf(l1[qi], l2[qi]));
                const float alpha = __expf(m_i[qi] - mn);
                const float p1    = __expf(l1[qi] - mn);
                const float p2    = __expf(l2[qi] - mn);
                m_i[qi] = mn;
                e_i[qi] = e_i[qi] * alpha + (p1 + p2);
                acc[qi].x = fmaf(acc[qi].x, alpha, fmaf(p1, v1.x, p2 * v2.x));
                acc[qi].y = fmaf(acc[qi].y, alpha, fmaf(p1, v1.y, p2 * v2.y));
                acc[qi].z = fmaf(acc[qi].z, alpha, fmaf(p1, v1.z, p2 * v2.z));
                acc[qi].w = fmaf(acc[qi].w, alpha, fmaf(p1, v1.w, p2 * v2.w));
            }
        }
        __syncthreads();   // buf reuse + prefetch completion barrier
        buf ^= 1;
    }

    // merge the 8 half-accumulators; sm_acc aliases smem (compute is done)
    float* sacc = smem;    // [hh][qi][d] = hh*512 + qi*128 + d  (16 KB)
#pragma unroll
    for (int qi = 0; qi < QPG; ++qi) {
        if (lane == 0) { sm_m[accid][qi] = m_i[qi]; sm_e[accid][qi] = e_i[qi]; }
        sacc[accid * 512 + qi * 128 + d0 + 0] = acc[qi].x;
        sacc[accid * 512 + qi * 128 + d0 + 1] = acc[qi].y;
        sacc[accid * 512 + qi * 128 + d0 + 2] = acc[qi].z;
        sacc[accid * 512 + qi * 128 + d0 + 3] = acc[qi].w;
    }
    __syncthreads();

    const int r = w * SPLIT + p;
    for (int pi = tid; pi < QPG * HEAD_SIZE; pi += 256) {
        const int qi = pi >> 7;
        const int d  = pi & (HEAD_SIZE - 1);
        float gm = NEG_BIG;
#pragma unroll
        for (int hh = 0; hh < 8; ++hh) gm = fmaxf(gm, sm_m[hh][qi]);
        float num = 0.f, den = 0.f;
#pragma unroll
        for (int hh = 0; hh < 8; ++hh) {
            const float sc = __expf(sm_m[hh][qi] - gm);   // empty half: e=0, acc=0
            num += sacc[hh * 512 + qi * 128 + d] * sc;
            den += sm_e[hh][qi] * sc;
        }
        const size_t idx = (((size_t)r * S + s) * G + g) * QPG + qi;
        acc_ws[idx * HEAD_SIZE + d] = num;
        if (d == 0) { m_ws[idx] = gm; e_ws[idx] = den; }
    }
}

// Kernel 2: LSE combine over NPART partials. One block per (s,g).
__global__ __launch_bounds__(256)
void pa_reduce_kernel(const float* __restrict__ acc_ws,
                      const float* __restrict__ m_ws,
                      const float* __restrict__ e_ws,
                      float* __restrict__ out)
{
    const int bx = blockIdx.x;       // s*G + g
    const int s = bx / G, g = bx % G;
    const int tid = threadIdx.x;
    for (int pi = tid; pi < QPG * HEAD_SIZE; pi += 256) {
        const int qi = pi >> 7;
        const int d  = pi & (HEAD_SIZE - 1);
        float mw[NPART], ew[NPART];
        float gm = NEG_BIG;
#pragma unroll
        for (int r = 0; r < NPART; ++r) {
            const size_t idx = (((size_t)r * S + s) * G + g) * QPG + qi;
            mw[r] = m_ws[idx];
            ew[r] = e_ws[idx];
            gm = fmaxf(gm, mw[r]);
        }
        float num = 0.f, den = 0.f;
#pragma unroll
        for (int r = 0; r < NPART; ++r) {
            const float sc = __expf(mw[r] - gm);
            const size_t idx = (((size_t)r * S + s) * G + g) * QPG + qi;
            num += acc_ws[idx * HEAD_SIZE + d] * sc;
            den += ew[r] * sc;
        }
        out[((size_t)s * NUM_HEADS + g * QPG + qi) * HEAD_SIZE + d] = num / den;
    }
}

// Fallback fused single-kernel path (no workspace). One block per (s,g).
__global__ __launch_bounds__(256)
void pa_fused_kernel(const float* __restrict__ query,
                     const float* __restrict__ key_cache,
                     const float* __restrict__ value_cache,
                     const int* __restrict__ block_tables,
                     const int* __restrict__ context_lens,
                     float* __restrict__ out)
{
    const int bx = blockIdx.x;
    const int s = bx / G, g = bx % G;
    const int tid   = threadIdx.x;
    const int accid = tid >> 5;
    const int lane  = tid & 31;
    const int d0    = lane * 4;

    __shared__ int   bt_lds[MAX_BLOCKS];
    __shared__ float sm_m[8][QPG];
    __shared__ float sm_e[8][QPG];
    __shared__ float sm_acc[8][QPG][HEAD_SIZE];

    float4 qf[QPG];
#pragma unroll
    for (int qi = 0; qi < QPG; ++qi)
        qf[qi] = *reinterpret_cast<const float4*>(
            query + ((size_t)s * NUM_HEADS + g * QPG + qi) * HEAD_SIZE + d0);

    float  m_i[QPG], e_i[QPG];
    float4 acc[QPG];
#pragma unroll
    for (int qi = 0; qi < QPG; ++qi) {
        m_i[qi] = NEG_BIG; e_i[qi] = 0.f;
        acc[qi] = make_float4(0.f, 0.f, 0.f, 0.f);
    }

    for (int w = 0; w < W; ++w) {
        __syncthreads();
        if (tid < MAX_BLOCKS)
            bt_lds[tid] = block_tables[((size_t)w * S + s) * MAX_BLOCKS + tid];
        __syncthreads();
        const int ctx = context_lens[w * S + s];
        const float* kbase = key_cache   + (size_t)w * WG_STRIDE + (size_t)g * CHUNK_ELEMS;
        const float* vbase = value_cache + (size_t)w * WG_STRIDE + (size_t)g * CHUNK_ELEMS;
        for (int t = accid; t < ctx; t += 8) {
            const int off = bt_lds[t >> 4] * BLK_STRIDE + (t & 15) * HEAD_SIZE + d0;
            const float4 kx = *reinterpret_cast<const float4*>(kbase + off);
            const float4 vx = *reinterpret_cast<const float4*>(vbase + off);
            float4 dv;
            dv.x = qf[0].x*kx.x + qf[0].y*kx.y + qf[0].z*kx.z + qf[0].w*kx.w;
            dv.y = qf[1].x*kx.x + qf[1].y*kx.y + qf[1].z*kx.z + qf[1].w*kx.w;
            dv.z = qf[2].x*kx.x + qf[2].y*kx.y + qf[2].z*kx.z + qf[2].w*kx.w;
            dv.w = qf[3].x*kx.x + qf[3].y*kx.y + qf[3].z*kx.z + qf[3].w*kx.w;
#pragma unroll
            for (int o = 16; o > 0; o >>= 1) {
                dv.x += __shfl_xor(dv.x, o); dv.y += __shfl_xor(dv.y, o);
                dv.z += __shfl_xor(dv.z, o); dv.w += __shfl_xor(dv.w, o);
            }
            const float lg[QPG] = {dv.x*SCALE, dv.y*SCALE, dv.z*SCALE, dv.w*SCALE};
#pragma unroll
            for (int qi = 0; qi < QPG; ++qi) {
                const float mn    = fmaxf(m_i[qi], lg[qi]);
                const float alpha = __expf(m_i[qi] - mn);
                const float pp    = __expf(lg[qi] - mn);
                m_i[qi] = mn;
                e_i[qi] = e_i[qi] * alpha + pp;
                acc[qi].x = fmaf(acc[qi].x, alpha, pp * vx.x);
                acc[qi].y = fmaf(acc[qi].y, alpha, pp * vx.y);
                acc[qi].z = fmaf(acc[qi].z, alpha, pp * vx.z);
                acc[qi].w = fmaf(acc[qi].w, alpha, pp * vx.w);
            }
        }
    }

#pragma unroll
    for (int qi = 0; qi < QPG; ++qi) {
        if (lane == 0) { sm_m[accid][qi] = m_i[qi]; sm_e[accid][qi] = e_i[qi]; }
        sm_acc[accid][qi][d0 + 0] = acc[qi].x;
        sm_acc[accid][qi][d0 + 1] = acc[qi].y;
        sm_acc[accid][qi][d0 + 2] = acc[qi].z;
        sm_acc[accid][qi][d0 + 3] = acc[qi].w;
    }
    __syncthreads();

    for (int pi = tid; pi < QPG * HEAD_SIZE; pi += 256) {
        const int qi = pi >> 7;
        const int d  = pi & (HEAD_SIZE - 1);
        float gm = NEG_BIG;
#pragma unroll
        for (int hh = 0; hh < 8; ++hh) gm = fmaxf(gm, sm_m[hh][qi]);
        float num = 0.f, den = 0.f;
#pragma unroll
        for (int hh = 0; hh < 8; ++hh) {
            const float sc = __expf(sm_m[hh][qi] - gm);
            num += sm_acc[hh][qi][d] * sc;
            den += sm_e[hh][qi] * sc;
        }
        out[((size_t)s * NUM_HEADS + g * QPG + qi) * HEAD_SIZE + d] = num / den;
    }
}

extern "C" void kernel_launch(void* const* d_in, const int* in_sizes, int n_in,
                              void* d_out, int out_size, void* d_ws, size_t ws_size,
                              hipStream_t stream) {
    const float* query        = (const float*)d_in[0];
    const float* key_cache    = (const float*)d_in[1];
    const float* value_cache  = (const float*)d_in[2];
    const int*   block_tables = (const int*)d_in[3];
    const int*   context_lens = (const int*)d_in[4];
    float* out = (float*)d_out;

    const size_t n_acc   = (size_t)NPART * S * G * QPG * HEAD_SIZE;
    const size_t n_stats = (size_t)NPART * S * G * QPG;
    const size_t need    = (n_acc + 2 * n_stats) * sizeof(float);

    if (ws_size >= need) {
        float* acc_ws = (float*)d_ws;
        float* m_ws   = acc_ws + n_acc;
        float* e_ws   = m_ws + n_stats;
        pa_partial_kernel<<<W * S * G * SPLIT, 256, 0, stream>>>(
            query, key_cache, value_cache, block_tables, context_lens,
            acc_ws, m_ws, e_ws);
        pa_reduce_kernel<<<S * G, 256, 0, stream>>>(acc_ws, m_ws, e_ws, out);
    } else {
        pa_fused_kernel<<<S * G, 256, 0, stream>>>(
            query, key_cache, value_cache, block_tables, context_lens, out);
    }
}